// Round 11
// baseline (215.816 us; speedup 1.0000x reference)
//
#include <hip/hip_runtime.h>
#include <math.h>

#define NT 20000
#define NW 5000
#define NS 1000

typedef __attribute__((ext_vector_type(8))) short bf16x8;
typedef __attribute__((ext_vector_type(4))) float f32x4;

// combine grid segmentation (float4 elements, 256/block, per-type aligned)
#define CB_T 1250   // 20000*16/256
#define CB_W 313    // ceil(5000*16/256)
#define CB_S 63     // ceil(1000*16/256)
#define CB_ALL 1626

// ---------------- tables ----------------
struct GemmSeg { const short* X; const short* Wt; short* Y; int N; int blk0; };
struct GemmTab { GemmSeg s[10]; int nseg; };

struct GatSeg { const int* rowp; const int* col; const short* xl; const short* xr;
                const float* att; const float* bias; float* agg; int Nd; int wave0; };
struct GatTab { GatSeg s[5]; int nseg; };

struct EdgeSeg { const int* ei; int* cnt; int* col; int E; int blk0; };
struct EdgeTab { EdgeSeg s[5]; int nseg; };

struct ScanTab { int* cnt[5]; int* rowp[5]; int n[5]; };

struct Mega0 {
  const float *xT, *xW, *xS, *WT, *WW, *WS;
  const float *bT, *gT, *beT, *bW, *gW, *beW, *bS, *gS, *beS;
  short *ybT, *ybW, *ybS;
  const float *gWl, *gWr; short *Wlt, *Wrt; int* nxtAll;
};

// ---------------- helpers ----------------
__device__ __forceinline__ float wsum64(float v) {
  #pragma unroll
  for (int o = 32; o > 0; o >>= 1) v += __shfl_xor(v, o, 64);
  return v;
}
__device__ __forceinline__ short f2b(float f) {   // f32 -> bf16 RNE
  unsigned u = __float_as_uint(f);
  unsigned r = (u + 0x7FFFu + ((u >> 16) & 1u)) >> 16;
  return (short)(unsigned short)r;
}
__device__ __forceinline__ float blo(unsigned x) { return __uint_as_float(x << 16); }
__device__ __forceinline__ float bhi(unsigned x) { return __uint_as_float(x & 0xFFFF0000u); }

// ---------------- mega0: embed (blocks 0..6499) | wprep+zero (6500..7779) ------------
// count must NOT live here — it reads nxtAll zeroed by sibling blocks (R6 race lesson).
// Embed output is bf16 ONLY: the residual chain runs in bf16.
__global__ void mega0_kernel(Mega0 M) {
  int b = blockIdx.x;
  if (b < 6500) {
    int gid = b * 256 + threadIdx.x;
    int wid = gid >> 6, lane = gid & 63;
    const float *x, *W, *bb, *gg, *be; short* yb; int FD, n;
    if (wid < NT)            { x = M.xT; W = M.WT; bb = M.bT; gg = M.gT; be = M.beT; yb = M.ybT; FD = 16; n = wid; }
    else if (wid < NT + NW)  { x = M.xW; W = M.WW; bb = M.bW; gg = M.gW; be = M.beW; yb = M.ybW; FD = 12; n = wid - NT; }
    else                     { x = M.xS; W = M.WS; bb = M.bS; gg = M.gS; be = M.beS; yb = M.ybS; FD = 10; n = wid - NT - NW; }
    const float* xr = x + (size_t)n * FD;
    float acc = bb[lane];
    for (int k = 0; k < FD; ++k) acc = fmaf(xr[k], W[k * 64 + lane], acc);
    float m = wsum64(acc) * (1.f / 64.f);
    float d = acc - m;
    float v = wsum64(d * d) * (1.f / 64.f);
    float o = d * rsqrtf(v + 1e-5f) * gg[lane] + be[lane];
    o = fmaxf(o, 0.f);
    yb[(size_t)n * 64 + lane] = f2b(o);
  } else {
    int idx = (b - 6500) * 256 + threadIdx.x;   // 0..327679
    if (idx < 66000) M.nxtAll[idx] = 0;
    int side = idx >= 163840;
    int j = idx - side * 163840;
    int m = j >> 14, e = j & 16383;
    int k = e >> 8, colv = e & 255;
    const float* src = side ? M.gWr : M.gWl;
    short* dst = side ? M.Wrt : M.Wlt;
    dst[m * 16384 + colv * 64 + k] = f2b(src[m * 16384 + e]);
  }
}

// ---------------- CSR: count / scan ----------------
__global__ void count_kernel(EdgeTab tab) {
  int b = blockIdx.x, si = 0;
  for (int i = 1; i < tab.nseg; ++i) if (b >= tab.s[i].blk0) si = i;
  EdgeSeg sg = tab.s[si];
  int e = (b - sg.blk0) * 256 + threadIdx.x;
  if (e < sg.E) atomicAdd(&sg.cnt[sg.ei[sg.E + e]], 1);
}

// int4-vectorized single-block scan: 4096 elems/chunk (n is a multiple of 4)
__global__ void scan_kernel(ScanTab tab) {
  int t = blockIdx.x;
  int4* cnt4  = (int4*)tab.cnt[t];
  int*  rowp  = tab.rowp[t];
  int4* rowp4 = (int4*)rowp;
  int n  = tab.n[t];
  int n4 = n >> 2;
  __shared__ int wsums[16];
  __shared__ int carry_s;
  int tid = threadIdx.x, lane = tid & 63, w = tid >> 6;
  if (tid == 0) carry_s = 0;
  __syncthreads();
  for (int base = 0; base < n4; base += 1024) {
    int i = base + tid;
    int4 v = (i < n4) ? cnt4[i] : make_int4(0, 0, 0, 0);
    int tsum = v.x + v.y + v.z + v.w;
    int s = tsum;
    #pragma unroll
    for (int o = 1; o < 64; o <<= 1) { int x = __shfl_up(s, o, 64); if (lane >= o) s += x; }
    if (lane == 63) wsums[w] = s;
    __syncthreads();
    if (w == 0 && lane < 16) {
      int x = wsums[lane];
      #pragma unroll
      for (int o = 1; o < 16; o <<= 1) { int y = __shfl_up(x, o, 16); if (lane >= o) x += y; }
      wsums[lane] = x;
    }
    __syncthreads();
    int carry   = carry_s;
    int waveoff = (w == 0) ? 0 : wsums[w - 1];
    int b0      = carry + waveoff + s - tsum;
    if (i < n4) {
      int4 e;
      e.x = b0; e.y = b0 + v.x; e.z = e.y + v.y; e.w = e.z + v.z;
      rowp4[i] = e;
      cnt4[i]  = e;
    }
    __syncthreads();
    if (tid == 0) carry_s += wsums[15];
    __syncthreads();
  }
  if (threadIdx.x == 0) rowp[n] = carry_s;
}

// ---------------- fill ∥ MFMA GEMM (merged dispatch) ----------------
// Blocks [0,fillBlocks): CSR fill (needs scan done; runs concurrent with gemm —
// disjoint writes, both consumed by the NEXT dispatch).
// Blocks [fillBlocks,...): Y[N,256](bf16) = X[N,64](bf16) @ W[64,256], 128-row tile.
__global__ __launch_bounds__(256, 3) void gemm_kernel(GemmTab tab, EdgeTab et, int fillBlocks) {
  __shared__ short lds[24576];   // 48 KB: X 8192 + Wt 16384; epilogue reuses [0,16896)
  int bx = blockIdx.x;
  if (bx < fillBlocks) {
    int si = 0;
    for (int i = 1; i < et.nseg; ++i) if (bx >= et.s[i].blk0) si = i;
    EdgeSeg sg = et.s[si];
    int e = (bx - sg.blk0) * 256 + threadIdx.x;
    if (e < sg.E) {
      int s = sg.ei[e], d = sg.ei[sg.E + e];
      int pos = atomicAdd(&sg.cnt[d], 1);
      sg.col[pos] = s;
    }
    return;
  }
  int b = bx - fillBlocks, si = 0;
  for (int i = 1; i < tab.nseg; ++i) if (b >= tab.s[i].blk0) si = i;
  GemmSeg sg = tab.s[si];
  int r0 = (b - sg.blk0) * 128;
  int tid = threadIdx.x;
  #pragma unroll
  for (int it = 0; it < 4; ++it) {              // stage X tile (128 rows, 16 KB)
    int idx = it * 256 + tid;
    int row = idx >> 3, kq = idx & 7;
    bf16x8 v = {0, 0, 0, 0, 0, 0, 0, 0};
    if (r0 + row < sg.N) v = *(const bf16x8*)&sg.X[(size_t)(r0 + row) * 64 + kq * 8];
    *(bf16x8*)&lds[(row * 8 + (kq ^ (row & 7))) * 8] = v;
  }
  #pragma unroll
  for (int it = 0; it < 8; ++it) {              // stage Wt (32 KB)
    int idx = it * 256 + tid;
    int col = idx >> 3, kq = idx & 7;
    bf16x8 v = *(const bf16x8*)&sg.Wt[col * 64 + kq * 8];
    *(bf16x8*)&lds[8192 + (col * 8 + (kq ^ (col & 7))) * 8] = v;
  }
  __syncthreads();
  int lane = tid & 63, wv = tid >> 6;
  int r = lane & 15, hk = lane >> 4;
  f32x4 acc[8][4];
  #pragma unroll
  for (int rt = 0; rt < 8; ++rt)
    #pragma unroll
    for (int ct = 0; ct < 4; ++ct) acc[rt][ct] = (f32x4){0.f, 0.f, 0.f, 0.f};
  #pragma unroll
  for (int kk = 0; kk < 2; ++kk) {
    int kq = kk * 4 + hk;
    bf16x8 bbv[4];
    #pragma unroll
    for (int ct = 0; ct < 4; ++ct) {
      int col = wv * 64 + ct * 16 + r;
      bbv[ct] = *(const bf16x8*)&lds[8192 + (col * 8 + (kq ^ (col & 7))) * 8];
    }
    #pragma unroll
    for (int rt = 0; rt < 8; ++rt) {
      int row = rt * 16 + r;
      bf16x8 a = *(const bf16x8*)&lds[(row * 8 + (kq ^ (row & 7))) * 8];
      #pragma unroll
      for (int ct = 0; ct < 4; ++ct)
        acc[rt][ct] = __builtin_amdgcn_mfma_f32_16x16x32_bf16(a, bbv[ct], acc[rt][ct], 0, 0, 0);
    }
  }
  // epilogue: two 64-row halves, LDS reused for coalesced repack
  #pragma unroll
  for (int hp = 0; hp < 2; ++hp) {
    __syncthreads();                             // staging reads (or prev stores) done
    #pragma unroll
    for (int rt4 = 0; rt4 < 4; ++rt4) {
      int rt = hp * 4 + rt4;
      #pragma unroll
      for (int j = 0; j < 4; ++j) {
        int rowl = rt4 * 16 + hk * 4 + j;        // C/D: col=lane&15, row=(lane>>4)*4+reg
        #pragma unroll
        for (int ct = 0; ct < 4; ++ct)
          lds[rowl * 264 + wv * 64 + ct * 16 + r] = f2b(acc[rt][ct][j]);
      }
    }
    __syncthreads();
    #pragma unroll
    for (int it = 0; it < 8; ++it) {             // coalesced bf16x8 stores
      int idx = it * 256 + tid;
      int rowl = idx >> 5, v8 = idx & 31;
      int row = hp * 64 + rowl;
      if (r0 + row < sg.N) {
        bf16x8 v = *(const bf16x8*)&lds[rowl * 264 + v8 * 8];
        *(bf16x8*)&sg.Y[(size_t)(r0 + row) * 256 + v8 * 8] = v;
      }
    }
  }
}

// ---------------- GATv2: wave per (dst node, relation) — R4-proven 2-deep loop -------
// Segment order: longest waves first (station deg~30, worker deg~8, then task rels).
__global__ void gat_kernel(GatTab tab) {
  int gwave = (blockIdx.x * blockDim.x + threadIdx.x) >> 6;
  int lane  = threadIdx.x & 63;
  int si = 0;
  for (int i = 1; i < tab.nseg; ++i) if (gwave >= tab.s[i].wave0) si = i;
  GatSeg sg = tab.s[si];
  int n = gwave - sg.wave0;
  if (n >= sg.Nd) return;
  int h = lane >> 4, lig = lane & 15;
  int beg = sg.rowp[n], end = sg.rowp[n + 1];
  uint2 xru = *(const uint2*)&sg.xr[(size_t)n * 256 + h * 64 + lig * 4];
  float4 a4 = *(const float4*)&sg.att[h * 64 + lig * 4];
  float xr0 = blo(xru.x), xr1 = bhi(xru.x), xr2 = blo(xru.y), xr3 = bhi(xru.y);
  float den = 0.f, c0 = 0.f, c1 = 0.f, c2 = 0.f, c3 = 0.f;
  if (end > beg) {
    int sNxt = sg.col[beg];
    uint2 w = *(const uint2*)&sg.xl[(size_t)sNxt * 256 + h * 64 + lig * 4];
    if (beg + 1 < end) sNxt = sg.col[beg + 1];
    for (int i = beg; i < end; ++i) {
      uint2 wc = w;
      if (i + 1 < end)
        w = *(const uint2*)&sg.xl[(size_t)sNxt * 256 + h * 64 + lig * 4];
      if (i + 2 < end) sNxt = sg.col[i + 2];
      float f0 = blo(wc.x), f1 = bhi(wc.x), f2v = blo(wc.y), f3 = bhi(wc.y);
      float vx = f0 + xr0, vy = f1 + xr1, vz = f2v + xr2, vw = f3 + xr3;
      vx = fmaxf(vx, 0.2f * vx); vy = fmaxf(vy, 0.2f * vy);
      vz = fmaxf(vz, 0.2f * vz); vw = fmaxf(vw, 0.2f * vw);
      float dd = fmaf(vx, a4.x, fmaf(vy, a4.y, fmaf(vz, a4.z, vw * a4.w)));
      dd += __shfl_xor(dd, 1, 64);
      dd += __shfl_xor(dd, 2, 64);
      dd += __shfl_xor(dd, 4, 64);
      dd += __shfl_xor(dd, 8, 64);
      float e = __expf(dd);                      // softmax shift-invariant; logits O(10)
      den += e;
      c0 = fmaf(e, f0, c0); c1 = fmaf(e, f1, c1);
      c2 = fmaf(e, f2v, c2); c3 = fmaf(e, f3, c3);
    }
  }
  float o0 = 0.f, o1 = 0.f, o2 = 0.f, o3 = 0.f;
  if (end > beg) {
    float inv = 1.f / den;
    o0 = c0 * inv; o1 = c1 * inv; o2 = c2 * inv; o3 = c3 * inv;
  }
  o0 += __shfl_xor(o0, 16, 64); o0 += __shfl_xor(o0, 32, 64);
  o1 += __shfl_xor(o1, 16, 64); o1 += __shfl_xor(o1, 32, 64);
  o2 += __shfl_xor(o2, 16, 64); o2 += __shfl_xor(o2, 32, 64);
  o3 += __shfl_xor(o3, 16, 64); o3 += __shfl_xor(o3, 32, 64);
  if (lane < 16) {
    float4 b4 = *(const float4*)&sg.bias[lane * 4];
    float4 res;
    res.x = fmaf(0.25f, o0, b4.x); res.y = fmaf(0.25f, o1, b4.y);
    res.z = fmaf(0.25f, o2, b4.z); res.w = fmaf(0.25f, o3, b4.w);
    *(float4*)&sg.agg[(size_t)n * 64 + lane * 4] = res;
  }
}

// ---------------- combine ----------------
// POOL=0 (layer 0): r = relu(sum aggs) + bf16(x);  writes bf16 xcb in-place.
// POOL=1 (layer 1): same r; writes f32 d_out slices + fused pool partials.
template <int POOL>
__global__ __launch_bounds__(256) void combine_kernel(
    const float4* __restrict__ aT0, const float4* __restrict__ aT2, const float4* __restrict__ aT3,
    const float4* __restrict__ aW, const float4* __restrict__ aS,
    const uint2* __restrict__ xT, const uint2* __restrict__ xW, const uint2* __restrict__ xS,
    float4* __restrict__ oT, float4* __restrict__ oW, float4* __restrict__ oS,
    uint2* __restrict__ bT, uint2* __restrict__ bW, uint2* __restrict__ bS,
    float4* __restrict__ psum, float4* __restrict__ pmax) {
  int b = blockIdx.x, tid = threadIdx.x;
  const float4 *a; const uint2* x; float4* o; uint2* bo; int n4, local; bool sum3 = false;
  const float4 *a2 = nullptr, *a3 = nullptr;
  if (b < CB_T)              { a = aT0; a2 = aT2; a3 = aT3; x = xT; o = oT; bo = bT; n4 = NT * 16; local = b; sum3 = true; }
  else if (b < CB_T + CB_W)  { a = aW; x = xW; o = oW; bo = bW; n4 = NW * 16; local = b - CB_T; }
  else                       { a = aS; x = xS; o = oS; bo = bS; n4 = NS * 16; local = b - CB_T - CB_W; }
  int j = local * 256 + tid;
  bool valid = j < n4;
  float4 r = make_float4(0.f, 0.f, 0.f, 0.f);
  if (valid) {
    float4 av = a[j];
    if (sum3) {
      float4 v2 = a2[j], v3 = a3[j];
      av.x += v2.x + v3.x; av.y += v2.y + v3.y; av.z += v2.z + v3.z; av.w += v2.w + v3.w;
    }
    uint2 xv = x[j];
    r.x = fmaxf(av.x, 0.f) + blo(xv.x); r.y = fmaxf(av.y, 0.f) + bhi(xv.x);
    r.z = fmaxf(av.z, 0.f) + blo(xv.y); r.w = fmaxf(av.w, 0.f) + bhi(xv.y);
    if (POOL == 0) {
      uint2 pk;
      pk.x = (unsigned)(unsigned short)f2b(r.x) | ((unsigned)(unsigned short)f2b(r.y) << 16);
      pk.y = (unsigned)(unsigned short)f2b(r.z) | ((unsigned)(unsigned short)f2b(r.w) << 16);
      bo[j] = pk;
    } else {
      o[j] = r;
    }
  }
  if (POOL) {
    float4 s = r;
    float4 m = valid ? r : make_float4(-3e38f, -3e38f, -3e38f, -3e38f);
    #pragma unroll
    for (int off = 16; off <= 32; off <<= 1) {
      s.x += __shfl_xor(s.x, off, 64); s.y += __shfl_xor(s.y, off, 64);
      s.z += __shfl_xor(s.z, off, 64); s.w += __shfl_xor(s.w, off, 64);
      m.x = fmaxf(m.x, __shfl_xor(m.x, off, 64)); m.y = fmaxf(m.y, __shfl_xor(m.y, off, 64));
      m.z = fmaxf(m.z, __shfl_xor(m.z, off, 64)); m.w = fmaxf(m.w, __shfl_xor(m.w, off, 64));
    }
    __shared__ float4 ls[4][16], lm[4][16];
    int w = tid >> 6, q = tid & 15;
    if (((tid >> 4) & 3) == 0) { ls[w][q] = s; lm[w][q] = m; }
    __syncthreads();
    if (tid < 16) {
      float4 S = ls[0][tid], M = lm[0][tid];
      #pragma unroll
      for (int i = 1; i < 4; ++i) {
        float4 s2 = ls[i][tid], m2 = lm[i][tid];
        S.x += s2.x; S.y += s2.y; S.z += s2.z; S.w += s2.w;
        M.x = fmaxf(M.x, m2.x); M.y = fmaxf(M.y, m2.y);
        M.z = fmaxf(M.z, m2.z); M.w = fmaxf(M.w, m2.w);
      }
      psum[b * 16 + tid] = S;
      pmax[b * 16 + tid] = M;
    }
  }
}

// ---------------- pool stage 2 ----------------
// gc layout: [s_mean, t_mean, w_mean, s_max, t_max, w_max] (64 each)
__global__ void pool2_kernel(const float* __restrict__ psum,
                             const float* __restrict__ pmax,
                             float* __restrict__ gc) {
  int b = blockIdx.x;  // 0 station, 1 task, 2 worker
  int lane = threadIdx.x & 63, w = threadIdx.x >> 6;
  int off, cnt, N, mi;
  if (b == 0)      { off = CB_T + CB_W; cnt = CB_S; N = NS; mi = 0;   }
  else if (b == 1) { off = 0;           cnt = CB_T; N = NT; mi = 64;  }
  else             { off = CB_T;        cnt = CB_W; N = NW; mi = 128; }
  float s = 0.f, mx = -3e38f;
  for (int i = w; i < cnt; i += 16) {
    s += psum[(size_t)(off + i) * 64 + lane];
    mx = fmaxf(mx, pmax[(size_t)(off + i) * 64 + lane]);
  }
  __shared__ float ss[16][64], sm[16][64];
  ss[w][lane] = s; sm[w][lane] = mx;
  __syncthreads();
  if (w == 0) {
    #pragma unroll
    for (int i = 1; i < 16; ++i) { s += ss[i][lane]; mx = fmaxf(mx, sm[i][lane]); }
    gc[mi + lane] = s / (float)N;
    gc[192 + mi + lane] = mx;
  }
}

// ---------------- driver ----------------
extern "C" void kernel_launch(void* const* d_in, const int* in_sizes, int n_in,
                              void* d_out, int out_size, void* d_ws, size_t ws_size,
                              hipStream_t stream) {
  const float* x_in[3] = {(const float*)d_in[0], (const float*)d_in[1], (const float*)d_in[2]};
  const int*   ei[5]   = {(const int*)d_in[3], (const int*)d_in[4], (const int*)d_in[5],
                          (const int*)d_in[6], (const int*)d_in[7]};
  const float* Wemb[3] = {(const float*)d_in[8],  (const float*)d_in[12], (const float*)d_in[16]};
  const float* bemb[3] = {(const float*)d_in[9],  (const float*)d_in[13], (const float*)d_in[17]};
  const float* gemb[3] = {(const float*)d_in[10], (const float*)d_in[14], (const float*)d_in[18]};
  const float* beemb[3]= {(const float*)d_in[11], (const float*)d_in[15], (const float*)d_in[19]};
  const float* gWl   = (const float*)d_in[20];
  const float* gWr   = (const float*)d_in[21];
  const float* gatt  = (const float*)d_in[22];
  const float* gbias = (const float*)d_in[23];

  const int NN[3]  = {NT, NW, NS};
  const int EC[5]  = {50000, 30000, 30000, 40000, 40000};
  const int STy[5] = {0, 0, 2, 1, 0};
  const int DTy[5] = {0, 2, 0, 0, 1};

  char* p = (char*)d_ws;
  auto alloc = [&](size_t bytes) -> void* {
    void* r = (void*)p;
    p += (bytes + 255) & ~(size_t)255;
    return r;
  };
  short* xcb[3];
  for (int k = 0; k < 3; ++k) xcb[k] = (short*)alloc((size_t)NN[k] * 64 * 2);
  float* aggT0 = (float*)alloc((size_t)NT * 64 * 4);
  float* aggT2 = (float*)alloc((size_t)NT * 64 * 4);
  float* aggT3 = (float*)alloc((size_t)NT * 64 * 4);
  float* aggW  = (float*)alloc((size_t)NW * 64 * 4);
  float* aggS  = (float*)alloc((size_t)NS * 64 * 4);
  float* aggOf[5] = {aggT0, aggS, aggT2, aggT3, aggW};
  int* nxtAll = (int*)alloc((size_t)66000 * 4);
  int  nxtOff[5] = {0, NT, NT + NS, 2 * NT + NS, 3 * NT + NS};
  int* nxt[5]; for (int t = 0; t < 5; ++t) nxt[t] = nxtAll + nxtOff[t];
  int *rowp[5], *col[5];
  for (int t = 0; t < 5; ++t) {
    rowp[t] = (int*)alloc((size_t)(NN[DTy[t]] + 1) * 4);
    col[t]  = (int*)alloc((size_t)EC[t] * 4);
  }
  float* psum = (float*)alloc((size_t)CB_ALL * 64 * 4);
  float* pmax = (float*)alloc((size_t)CB_ALL * 64 * 4);
  short* Wlt  = (short*)alloc((size_t)10 * 16384 * 2);
  short* Wrt  = (short*)alloc((size_t)10 * 16384 * 2);
  short *xlT[5], *xrT[5];
  for (int t = 0; t < 5; ++t) {
    xlT[t] = (short*)alloc((size_t)NN[STy[t]] * 256 * 2);
    xrT[t] = (short*)alloc((size_t)NN[DTy[t]] * 256 * 2);
  }

  // edge table (blk0 relative to count/fill block ranges)
  EdgeTab etab; etab.nseg = 5;
  int eb = 0;
  for (int t = 0; t < 5; ++t) {
    etab.s[t] = {ei[t], nxt[t], col[t], EC[t], eb};
    eb += (EC[t] + 255) / 256;
  }

  // 0) mega0: embed(bf16-only) | wprep+zero (count separate — ordering!)
  Mega0 M;
  M.xT = x_in[0]; M.xW = x_in[1]; M.xS = x_in[2];
  M.WT = Wemb[0]; M.WW = Wemb[1]; M.WS = Wemb[2];
  M.bT = bemb[0]; M.gT = gemb[0]; M.beT = beemb[0];
  M.bW = bemb[1]; M.gW = gemb[1]; M.beW = beemb[1];
  M.bS = bemb[2]; M.gS = gemb[2]; M.beS = beemb[2];
  M.ybT = xcb[0]; M.ybW = xcb[1]; M.ybS = xcb[2];
  M.gWl = gWl; M.gWr = gWr; M.Wlt = Wlt; M.Wrt = Wrt; M.nxtAll = nxtAll;
  mega0_kernel<<<7780, 256, 0, stream>>>(M);

  // 1) CSR: count, scan  (fill is merged into the layer-0 gemm dispatch)
  count_kernel<<<eb, 256, 0, stream>>>(etab);
  ScanTab stab;
  for (int t = 0; t < 5; ++t) { stab.cnt[t] = nxt[t]; stab.rowp[t] = rowp[t]; stab.n[t] = NN[DTy[t]]; }
  scan_kernel<<<5, 1024, 0, stream>>>(stab);

  float* outT = (float*)d_out;
  float* outW = outT + (size_t)NT * 64;
  float* outS = outW + (size_t)NW * 64;
  float* gc   = outS + (size_t)NS * 64;

  // 2) GAT layers
  for (int l = 0; l < 2; ++l) {
    GemmTab gt; gt.nseg = 10;
    int gb = 0;
    for (int t = 0; t < 5; ++t) {
      size_t off = (size_t)(l * 5 + t);
      gt.s[2 * t + 0] = {xcb[STy[t]], Wlt + off * 16384, xlT[t], NN[STy[t]], gb};
      gb += (NN[STy[t]] + 127) / 128;
      gt.s[2 * t + 1] = {xcb[DTy[t]], Wrt + off * 16384, xrT[t], NN[DTy[t]], gb};
      gb += (NN[DTy[t]] + 127) / 128;
    }
    int fb = (l == 0) ? eb : 0;                 // layer 0: fill runs alongside gemm
    gemm_kernel<<<fb + gb, 256, 0, stream>>>(gt, etab, fb);

    // gat: longest segments first (station rel1 deg~30, worker rel4 deg~8, then task rels)
    GatTab at; at.nseg = 5;
    const int order[5] = {1, 4, 0, 2, 3};
    int wv = 0;
    for (int oi = 0; oi < 5; ++oi) {
      int t = order[oi];
      size_t off = (size_t)(l * 5 + t);
      at.s[oi] = {rowp[t], col[t], xlT[t], xrT[t], gatt + off * 256, gbias + off * 64,
                  aggOf[t], NN[DTy[t]], wv};
      wv += NN[DTy[t]];
    }
    gat_kernel<<<(wv * 64) / 256, 256, 0, stream>>>(at);

    if (l == 0) {
      combine_kernel<0><<<CB_ALL, 256, 0, stream>>>(
          (const float4*)aggT0, (const float4*)aggT2, (const float4*)aggT3,
          (const float4*)aggW, (const float4*)aggS,
          (const uint2*)xcb[0], (const uint2*)xcb[1], (const uint2*)xcb[2],
          nullptr, nullptr, nullptr,
          (uint2*)xcb[0], (uint2*)xcb[1], (uint2*)xcb[2],
          nullptr, nullptr);
    } else {
      combine_kernel<1><<<CB_ALL, 256, 0, stream>>>(
          (const float4*)aggT0, (const float4*)aggT2, (const float4*)aggT3,
          (const float4*)aggW, (const float4*)aggS,
          (const uint2*)xcb[0], (const uint2*)xcb[1], (const uint2*)xcb[2],
          (float4*)outT, (float4*)outW, (float4*)outS,
          nullptr, nullptr, nullptr,
          (float4*)psum, (float4*)pmax);
    }
  }

  // 3) final pool reduce
  pool2_kernel<<<3, 1024, 0, stream>>>(psum, pmax, gc);
}

// Round 12
// 207.680 us; speedup vs baseline: 1.0392x; 1.0392x over previous
//
#include <hip/hip_runtime.h>
#include <math.h>

#define NT 20000
#define NW 5000
#define NS 1000

typedef __attribute__((ext_vector_type(8))) short bf16x8;
typedef __attribute__((ext_vector_type(4))) float f32x4;

// combine grid segmentation (float4 elements, 256/block, per-type aligned)
#define CB_T 1250   // 20000*16/256
#define CB_W 313    // ceil(5000*16/256)
#define CB_S 63     // ceil(1000*16/256)
#define CB_ALL 1626

// ---------------- tables ----------------
struct GemmSeg { const short* X; const short* Wt; short* Y; int N; int blk0; };
struct GemmTab { GemmSeg s[10]; int nseg; };

struct GatSeg { const int* rowp; const int* col; const short* xl; const short* xr;
                const float* att; const float* bias; float* agg; int Nd; int wave0; };
struct GatTab { GatSeg s[5]; int nseg; };

struct EdgeSeg { const int* ei; int* cnt; int* col; int E; int blk0; };
struct EdgeTab { EdgeSeg s[5]; int nseg; };

struct ScanTab { int* cnt[5]; int* rowp[5]; int n[5]; };

struct Mega0 {
  const float *xT, *xW, *xS, *WT, *WW, *WS;
  const float *bT, *gT, *beT, *bW, *gW, *beW, *bS, *gS, *beS;
  short *ybT, *ybW, *ybS;
  const float *gWl, *gWr; short *Wlt, *Wrt; int* nxtAll;
};

// ---------------- helpers ----------------
__device__ __forceinline__ float wsum64(float v) {
  #pragma unroll
  for (int o = 32; o > 0; o >>= 1) v += __shfl_xor(v, o, 64);
  return v;
}
__device__ __forceinline__ short f2b(float f) {   // f32 -> bf16 RNE
  unsigned u = __float_as_uint(f);
  unsigned r = (u + 0x7FFFu + ((u >> 16) & 1u)) >> 16;
  return (short)(unsigned short)r;
}
__device__ __forceinline__ float blo(unsigned x) { return __uint_as_float(x << 16); }
__device__ __forceinline__ float bhi(unsigned x) { return __uint_as_float(x & 0xFFFF0000u); }

// ---------------- mega0: embed (blocks 0..6499) | wprep+zero (6500..7779) ------------
// count must NOT live here — it reads nxtAll zeroed by sibling blocks (R6 race lesson).
// Embed output is bf16 ONLY: the residual chain runs in bf16.
__global__ void mega0_kernel(Mega0 M) {
  int b = blockIdx.x;
  if (b < 6500) {
    int gid = b * 256 + threadIdx.x;
    int wid = gid >> 6, lane = gid & 63;
    const float *x, *W, *bb, *gg, *be; short* yb; int FD, n;
    if (wid < NT)            { x = M.xT; W = M.WT; bb = M.bT; gg = M.gT; be = M.beT; yb = M.ybT; FD = 16; n = wid; }
    else if (wid < NT + NW)  { x = M.xW; W = M.WW; bb = M.bW; gg = M.gW; be = M.beW; yb = M.ybW; FD = 12; n = wid - NT; }
    else                     { x = M.xS; W = M.WS; bb = M.bS; gg = M.gS; be = M.beS; yb = M.ybS; FD = 10; n = wid - NT - NW; }
    const float* xr = x + (size_t)n * FD;
    float acc = bb[lane];
    for (int k = 0; k < FD; ++k) acc = fmaf(xr[k], W[k * 64 + lane], acc);
    float m = wsum64(acc) * (1.f / 64.f);
    float d = acc - m;
    float v = wsum64(d * d) * (1.f / 64.f);
    float o = d * rsqrtf(v + 1e-5f) * gg[lane] + be[lane];
    o = fmaxf(o, 0.f);
    yb[(size_t)n * 64 + lane] = f2b(o);
  } else {
    int idx = (b - 6500) * 256 + threadIdx.x;   // 0..327679
    if (idx < 66000) M.nxtAll[idx] = 0;
    int side = idx >= 163840;
    int j = idx - side * 163840;
    int m = j >> 14, e = j & 16383;
    int k = e >> 8, colv = e & 255;
    const float* src = side ? M.gWr : M.gWl;
    short* dst = side ? M.Wrt : M.Wlt;
    dst[m * 16384 + colv * 64 + k] = f2b(src[m * 16384 + e]);
  }
}

// ---------------- CSR: count / scan ----------------
__global__ void count_kernel(EdgeTab tab) {
  int b = blockIdx.x, si = 0;
  for (int i = 1; i < tab.nseg; ++i) if (b >= tab.s[i].blk0) si = i;
  EdgeSeg sg = tab.s[si];
  int e = (b - sg.blk0) * 256 + threadIdx.x;
  if (e < sg.E) atomicAdd(&sg.cnt[sg.ei[sg.E + e]], 1);
}

// int4-vectorized single-block scan: 4096 elems/chunk (n is a multiple of 4)
__global__ void scan_kernel(ScanTab tab) {
  int t = blockIdx.x;
  int4* cnt4  = (int4*)tab.cnt[t];
  int*  rowp  = tab.rowp[t];
  int4* rowp4 = (int4*)rowp;
  int n  = tab.n[t];
  int n4 = n >> 2;
  __shared__ int wsums[16];
  __shared__ int carry_s;
  int tid = threadIdx.x, lane = tid & 63, w = tid >> 6;
  if (tid == 0) carry_s = 0;
  __syncthreads();
  for (int base = 0; base < n4; base += 1024) {
    int i = base + tid;
    int4 v = (i < n4) ? cnt4[i] : make_int4(0, 0, 0, 0);
    int tsum = v.x + v.y + v.z + v.w;
    int s = tsum;
    #pragma unroll
    for (int o = 1; o < 64; o <<= 1) { int x = __shfl_up(s, o, 64); if (lane >= o) s += x; }
    if (lane == 63) wsums[w] = s;
    __syncthreads();
    if (w == 0 && lane < 16) {
      int x = wsums[lane];
      #pragma unroll
      for (int o = 1; o < 16; o <<= 1) { int y = __shfl_up(x, o, 16); if (lane >= o) x += y; }
      wsums[lane] = x;
    }
    __syncthreads();
    int carry   = carry_s;
    int waveoff = (w == 0) ? 0 : wsums[w - 1];
    int b0      = carry + waveoff + s - tsum;
    if (i < n4) {
      int4 e;
      e.x = b0; e.y = b0 + v.x; e.z = e.y + v.y; e.w = e.z + v.z;
      rowp4[i] = e;
      cnt4[i]  = e;
    }
    __syncthreads();
    if (tid == 0) carry_s += wsums[15];
    __syncthreads();
  }
  if (threadIdx.x == 0) rowp[n] = carry_s;
}

// ---------------- fill ∥ MFMA GEMM (merged dispatch; R10 64-row tile) ----------------
// Blocks [0,fillBlocks): CSR fill (needs scan done; concurrent with gemm — disjoint
// writes, both consumed by the NEXT dispatch).
// Blocks [fillBlocks,...): Y[N,256](bf16) = X[N,64](bf16) @ W[64,256], 64-row tile.
__global__ __launch_bounds__(256) void gemm_kernel(GemmTab tab, EdgeTab et, int fillBlocks) {
  __shared__ short lds[4096 + 16896];
  int bx = blockIdx.x;
  if (bx < fillBlocks) {
    int si = 0;
    for (int i = 1; i < et.nseg; ++i) if (bx >= et.s[i].blk0) si = i;
    EdgeSeg sg = et.s[si];
    int e = (bx - sg.blk0) * 256 + threadIdx.x;
    if (e < sg.E) {
      int s = sg.ei[e], d = sg.ei[sg.E + e];
      int pos = atomicAdd(&sg.cnt[d], 1);
      sg.col[pos] = s;
    }
    return;
  }
  int b = bx - fillBlocks, si = 0;
  for (int i = 1; i < tab.nseg; ++i) if (b >= tab.s[i].blk0) si = i;
  GemmSeg sg = tab.s[si];
  int r0 = (b - sg.blk0) * 64;
  int tid = threadIdx.x;
  #pragma unroll
  for (int it = 0; it < 2; ++it) {              // stage X tile
    int idx = it * 256 + tid;
    int row = idx >> 3, kq = idx & 7;
    bf16x8 v = {0, 0, 0, 0, 0, 0, 0, 0};
    if (r0 + row < sg.N) v = *(const bf16x8*)&sg.X[(size_t)(r0 + row) * 64 + kq * 8];
    *(bf16x8*)&lds[(row * 8 + (kq ^ (row & 7))) * 8] = v;
  }
  #pragma unroll
  for (int it = 0; it < 8; ++it) {              // stage Wt
    int idx = it * 256 + tid;
    int col = idx >> 3, kq = idx & 7;
    bf16x8 v = *(const bf16x8*)&sg.Wt[col * 64 + kq * 8];
    *(bf16x8*)&lds[4096 + (col * 8 + (kq ^ (col & 7))) * 8] = v;
  }
  __syncthreads();
  int lane = tid & 63, wv = tid >> 6;
  int r = lane & 15, hk = lane >> 4;
  f32x4 acc[4][4];
  #pragma unroll
  for (int rt = 0; rt < 4; ++rt)
    #pragma unroll
    for (int ct = 0; ct < 4; ++ct) acc[rt][ct] = (f32x4){0.f, 0.f, 0.f, 0.f};
  #pragma unroll
  for (int kk = 0; kk < 2; ++kk) {
    int kq = kk * 4 + hk;
    bf16x8 a[4], bb[4];
    #pragma unroll
    for (int rt = 0; rt < 4; ++rt) {
      int row = rt * 16 + r;
      a[rt] = *(const bf16x8*)&lds[(row * 8 + (kq ^ (row & 7))) * 8];
    }
    #pragma unroll
    for (int ct = 0; ct < 4; ++ct) {
      int col = wv * 64 + ct * 16 + r;
      bb[ct] = *(const bf16x8*)&lds[4096 + (col * 8 + (kq ^ (col & 7))) * 8];
    }
    #pragma unroll
    for (int rt = 0; rt < 4; ++rt)
      #pragma unroll
      for (int ct = 0; ct < 4; ++ct)
        acc[rt][ct] = __builtin_amdgcn_mfma_f32_16x16x32_bf16(a[rt], bb[ct], acc[rt][ct], 0, 0, 0);
  }
  __syncthreads();                               // LDS reuse: C repack
  #pragma unroll
  for (int rt = 0; rt < 4; ++rt)
    #pragma unroll
    for (int j = 0; j < 4; ++j) {
      int rowl = rt * 16 + hk * 4 + j;           // C/D: col=lane&15, row=(lane>>4)*4+reg
      #pragma unroll
      for (int ct = 0; ct < 4; ++ct)
        lds[rowl * 264 + wv * 64 + ct * 16 + r] = f2b(acc[rt][ct][j]);
    }
  __syncthreads();
  #pragma unroll
  for (int it = 0; it < 8; ++it) {               // coalesced bf16x8 stores
    int idx = it * 256 + tid;
    int row = idx >> 5, v8 = idx & 31;
    if (r0 + row < sg.N) {
      bf16x8 v = *(const bf16x8*)&lds[row * 264 + v8 * 8];
      *(bf16x8*)&sg.Y[(size_t)(r0 + row) * 256 + v8 * 8] = v;
    }
  }
}

// ---------------- GATv2: wave per (dst node, relation) — R4-proven 2-deep loop -------
// Segment order: longest waves first (station deg~30, worker deg~8, then task rels).
__global__ void gat_kernel(GatTab tab) {
  int gwave = (blockIdx.x * blockDim.x + threadIdx.x) >> 6;
  int lane  = threadIdx.x & 63;
  int si = 0;
  for (int i = 1; i < tab.nseg; ++i) if (gwave >= tab.s[i].wave0) si = i;
  GatSeg sg = tab.s[si];
  int n = gwave - sg.wave0;
  if (n >= sg.Nd) return;
  int h = lane >> 4, lig = lane & 15;
  int beg = sg.rowp[n], end = sg.rowp[n + 1];
  uint2 xru = *(const uint2*)&sg.xr[(size_t)n * 256 + h * 64 + lig * 4];
  float4 a4 = *(const float4*)&sg.att[h * 64 + lig * 4];
  float xr0 = blo(xru.x), xr1 = bhi(xru.x), xr2 = blo(xru.y), xr3 = bhi(xru.y);
  float den = 0.f, c0 = 0.f, c1 = 0.f, c2 = 0.f, c3 = 0.f;
  if (end > beg) {
    int sNxt = sg.col[beg];
    uint2 w = *(const uint2*)&sg.xl[(size_t)sNxt * 256 + h * 64 + lig * 4];
    if (beg + 1 < end) sNxt = sg.col[beg + 1];
    for (int i = beg; i < end; ++i) {
      uint2 wc = w;
      if (i + 1 < end)
        w = *(const uint2*)&sg.xl[(size_t)sNxt * 256 + h * 64 + lig * 4];
      if (i + 2 < end) sNxt = sg.col[i + 2];
      float f0 = blo(wc.x), f1 = bhi(wc.x), f2v = blo(wc.y), f3 = bhi(wc.y);
      float vx = f0 + xr0, vy = f1 + xr1, vz = f2v + xr2, vw = f3 + xr3;
      vx = fmaxf(vx, 0.2f * vx); vy = fmaxf(vy, 0.2f * vy);
      vz = fmaxf(vz, 0.2f * vz); vw = fmaxf(vw, 0.2f * vw);
      float dd = fmaf(vx, a4.x, fmaf(vy, a4.y, fmaf(vz, a4.z, vw * a4.w)));
      dd += __shfl_xor(dd, 1, 64);
      dd += __shfl_xor(dd, 2, 64);
      dd += __shfl_xor(dd, 4, 64);
      dd += __shfl_xor(dd, 8, 64);
      float e = __expf(dd);                      // softmax shift-invariant; logits O(10)
      den += e;
      c0 = fmaf(e, f0, c0); c1 = fmaf(e, f1, c1);
      c2 = fmaf(e, f2v, c2); c3 = fmaf(e, f3, c3);
    }
  }
  float o0 = 0.f, o1 = 0.f, o2 = 0.f, o3 = 0.f;
  if (end > beg) {
    float inv = 1.f / den;
    o0 = c0 * inv; o1 = c1 * inv; o2 = c2 * inv; o3 = c3 * inv;
  }
  o0 += __shfl_xor(o0, 16, 64); o0 += __shfl_xor(o0, 32, 64);
  o1 += __shfl_xor(o1, 16, 64); o1 += __shfl_xor(o1, 32, 64);
  o2 += __shfl_xor(o2, 16, 64); o2 += __shfl_xor(o2, 32, 64);
  o3 += __shfl_xor(o3, 16, 64); o3 += __shfl_xor(o3, 32, 64);
  if (lane < 16) {
    float4 b4 = *(const float4*)&sg.bias[lane * 4];
    float4 res;
    res.x = fmaf(0.25f, o0, b4.x); res.y = fmaf(0.25f, o1, b4.y);
    res.z = fmaf(0.25f, o2, b4.z); res.w = fmaf(0.25f, o3, b4.w);
    *(float4*)&sg.agg[(size_t)n * 64 + lane * 4] = res;
  }
}

// ---------------- combine ----------------
// POOL=0 (layer 0): r = relu(sum aggs) + bf16(x);  writes bf16 xcb in-place.
// POOL=1 (layer 1): same r; writes f32 d_out slices + fused pool partials.
template <int POOL>
__global__ __launch_bounds__(256) void combine_kernel(
    const float4* __restrict__ aT0, const float4* __restrict__ aT2, const float4* __restrict__ aT3,
    const float4* __restrict__ aW, const float4* __restrict__ aS,
    const uint2* __restrict__ xT, const uint2* __restrict__ xW, const uint2* __restrict__ xS,
    float4* __restrict__ oT, float4* __restrict__ oW, float4* __restrict__ oS,
    uint2* __restrict__ bT, uint2* __restrict__ bW, uint2* __restrict__ bS,
    float4* __restrict__ psum, float4* __restrict__ pmax) {
  int b = blockIdx.x, tid = threadIdx.x;
  const float4 *a; const uint2* x; float4* o; uint2* bo; int n4, local; bool sum3 = false;
  const float4 *a2 = nullptr, *a3 = nullptr;
  if (b < CB_T)              { a = aT0; a2 = aT2; a3 = aT3; x = xT; o = oT; bo = bT; n4 = NT * 16; local = b; sum3 = true; }
  else if (b < CB_T + CB_W)  { a = aW; x = xW; o = oW; bo = bW; n4 = NW * 16; local = b - CB_T; }
  else                       { a = aS; x = xS; o = oS; bo = bS; n4 = NS * 16; local = b - CB_T - CB_W; }
  int j = local * 256 + tid;
  bool valid = j < n4;
  float4 r = make_float4(0.f, 0.f, 0.f, 0.f);
  if (valid) {
    float4 av = a[j];
    if (sum3) {
      float4 v2 = a2[j], v3 = a3[j];
      av.x += v2.x + v3.x; av.y += v2.y + v3.y; av.z += v2.z + v3.z; av.w += v2.w + v3.w;
    }
    uint2 xv = x[j];
    r.x = fmaxf(av.x, 0.f) + blo(xv.x); r.y = fmaxf(av.y, 0.f) + bhi(xv.x);
    r.z = fmaxf(av.z, 0.f) + blo(xv.y); r.w = fmaxf(av.w, 0.f) + bhi(xv.y);
    if (POOL == 0) {
      uint2 pk;
      pk.x = (unsigned)(unsigned short)f2b(r.x) | ((unsigned)(unsigned short)f2b(r.y) << 16);
      pk.y = (unsigned)(unsigned short)f2b(r.z) | ((unsigned)(unsigned short)f2b(r.w) << 16);
      bo[j] = pk;
    } else {
      o[j] = r;
    }
  }
  if (POOL) {
    float4 s = r;
    float4 m = valid ? r : make_float4(-3e38f, -3e38f, -3e38f, -3e38f);
    #pragma unroll
    for (int off = 16; off <= 32; off <<= 1) {
      s.x += __shfl_xor(s.x, off, 64); s.y += __shfl_xor(s.y, off, 64);
      s.z += __shfl_xor(s.z, off, 64); s.w += __shfl_xor(s.w, off, 64);
      m.x = fmaxf(m.x, __shfl_xor(m.x, off, 64)); m.y = fmaxf(m.y, __shfl_xor(m.y, off, 64));
      m.z = fmaxf(m.z, __shfl_xor(m.z, off, 64)); m.w = fmaxf(m.w, __shfl_xor(m.w, off, 64));
    }
    __shared__ float4 ls[4][16], lm[4][16];
    int w = tid >> 6, q = tid & 15;
    if (((tid >> 4) & 3) == 0) { ls[w][q] = s; lm[w][q] = m; }
    __syncthreads();
    if (tid < 16) {
      float4 S = ls[0][tid], M = lm[0][tid];
      #pragma unroll
      for (int i = 1; i < 4; ++i) {
        float4 s2 = ls[i][tid], m2 = lm[i][tid];
        S.x += s2.x; S.y += s2.y; S.z += s2.z; S.w += s2.w;
        M.x = fmaxf(M.x, m2.x); M.y = fmaxf(M.y, m2.y);
        M.z = fmaxf(M.z, m2.z); M.w = fmaxf(M.w, m2.w);
      }
      psum[b * 16 + tid] = S;
      pmax[b * 16 + tid] = M;
    }
  }
}

// ---------------- pool stage 2 ----------------
// gc layout: [s_mean, t_mean, w_mean, s_max, t_max, w_max] (64 each)
__global__ void pool2_kernel(const float* __restrict__ psum,
                             const float* __restrict__ pmax,
                             float* __restrict__ gc) {
  int b = blockIdx.x;  // 0 station, 1 task, 2 worker
  int lane = threadIdx.x & 63, w = threadIdx.x >> 6;
  int off, cnt, N, mi;
  if (b == 0)      { off = CB_T + CB_W; cnt = CB_S; N = NS; mi = 0;   }
  else if (b == 1) { off = 0;           cnt = CB_T; N = NT; mi = 64;  }
  else             { off = CB_T;        cnt = CB_W; N = NW; mi = 128; }
  float s = 0.f, mx = -3e38f;
  for (int i = w; i < cnt; i += 16) {
    s += psum[(size_t)(off + i) * 64 + lane];
    mx = fmaxf(mx, pmax[(size_t)(off + i) * 64 + lane]);
  }
  __shared__ float ss[16][64], sm[16][64];
  ss[w][lane] = s; sm[w][lane] = mx;
  __syncthreads();
  if (w == 0) {
    #pragma unroll
    for (int i = 1; i < 16; ++i) { s += ss[i][lane]; mx = fmaxf(mx, sm[i][lane]); }
    gc[mi + lane] = s / (float)N;
    gc[192 + mi + lane] = mx;
  }
}

// ---------------- driver ----------------
extern "C" void kernel_launch(void* const* d_in, const int* in_sizes, int n_in,
                              void* d_out, int out_size, void* d_ws, size_t ws_size,
                              hipStream_t stream) {
  const float* x_in[3] = {(const float*)d_in[0], (const float*)d_in[1], (const float*)d_in[2]};
  const int*   ei[5]   = {(const int*)d_in[3], (const int*)d_in[4], (const int*)d_in[5],
                          (const int*)d_in[6], (const int*)d_in[7]};
  const float* Wemb[3] = {(const float*)d_in[8],  (const float*)d_in[12], (const float*)d_in[16]};
  const float* bemb[3] = {(const float*)d_in[9],  (const float*)d_in[13], (const float*)d_in[17]};
  const float* gemb[3] = {(const float*)d_in[10], (const float*)d_in[14], (const float*)d_in[18]};
  const float* beemb[3]= {(const float*)d_in[11], (const float*)d_in[15], (const float*)d_in[19]};
  const float* gWl   = (const float*)d_in[20];
  const float* gWr   = (const float*)d_in[21];
  const float* gatt  = (const float*)d_in[22];
  const float* gbias = (const float*)d_in[23];

  const int NN[3]  = {NT, NW, NS};
  const int EC[5]  = {50000, 30000, 30000, 40000, 40000};
  const int STy[5] = {0, 0, 2, 1, 0};
  const int DTy[5] = {0, 2, 0, 0, 1};

  char* p = (char*)d_ws;
  auto alloc = [&](size_t bytes) -> void* {
    void* r = (void*)p;
    p += (bytes + 255) & ~(size_t)255;
    return r;
  };
  short* xcb[3];
  for (int k = 0; k < 3; ++k) xcb[k] = (short*)alloc((size_t)NN[k] * 64 * 2);
  float* aggT0 = (float*)alloc((size_t)NT * 64 * 4);
  float* aggT2 = (float*)alloc((size_t)NT * 64 * 4);
  float* aggT3 = (float*)alloc((size_t)NT * 64 * 4);
  float* aggW  = (float*)alloc((size_t)NW * 64 * 4);
  float* aggS  = (float*)alloc((size_t)NS * 64 * 4);
  float* aggOf[5] = {aggT0, aggS, aggT2, aggT3, aggW};
  int* nxtAll = (int*)alloc((size_t)66000 * 4);
  int  nxtOff[5] = {0, NT, NT + NS, 2 * NT + NS, 3 * NT + NS};
  int* nxt[5]; for (int t = 0; t < 5; ++t) nxt[t] = nxtAll + nxtOff[t];
  int *rowp[5], *col[5];
  for (int t = 0; t < 5; ++t) {
    rowp[t] = (int*)alloc((size_t)(NN[DTy[t]] + 1) * 4);
    col[t]  = (int*)alloc((size_t)EC[t] * 4);
  }
  float* psum = (float*)alloc((size_t)CB_ALL * 64 * 4);
  float* pmax = (float*)alloc((size_t)CB_ALL * 64 * 4);
  short* Wlt  = (short*)alloc((size_t)10 * 16384 * 2);
  short* Wrt  = (short*)alloc((size_t)10 * 16384 * 2);
  short *xlT[5], *xrT[5];
  for (int t = 0; t < 5; ++t) {
    xlT[t] = (short*)alloc((size_t)NN[STy[t]] * 256 * 2);
    xrT[t] = (short*)alloc((size_t)NN[DTy[t]] * 256 * 2);
  }

  // edge table (blk0 relative to count/fill block ranges)
  EdgeTab etab; etab.nseg = 5;
  int eb = 0;
  for (int t = 0; t < 5; ++t) {
    etab.s[t] = {ei[t], nxt[t], col[t], EC[t], eb};
    eb += (EC[t] + 255) / 256;
  }

  // 0) mega0: embed(bf16-only) | wprep+zero (count separate — ordering!)
  Mega0 M;
  M.xT = x_in[0]; M.xW = x_in[1]; M.xS = x_in[2];
  M.WT = Wemb[0]; M.WW = Wemb[1]; M.WS = Wemb[2];
  M.bT = bemb[0]; M.gT = gemb[0]; M.beT = beemb[0];
  M.bW = bemb[1]; M.gW = gemb[1]; M.beW = beemb[1];
  M.bS = bemb[2]; M.gS = gemb[2]; M.beS = beemb[2];
  M.ybT = xcb[0]; M.ybW = xcb[1]; M.ybS = xcb[2];
  M.gWl = gWl; M.gWr = gWr; M.Wlt = Wlt; M.Wrt = Wrt; M.nxtAll = nxtAll;
  mega0_kernel<<<7780, 256, 0, stream>>>(M);

  // 1) CSR: count, scan  (fill merged into layer-0 gemm dispatch)
  count_kernel<<<eb, 256, 0, stream>>>(etab);
  ScanTab stab;
  for (int t = 0; t < 5; ++t) { stab.cnt[t] = nxt[t]; stab.rowp[t] = rowp[t]; stab.n[t] = NN[DTy[t]]; }
  scan_kernel<<<5, 1024, 0, stream>>>(stab);

  float* outT = (float*)d_out;
  float* outW = outT + (size_t)NT * 64;
  float* outS = outW + (size_t)NW * 64;
  float* gc   = outS + (size_t)NS * 64;

  // 2) GAT layers
  for (int l = 0; l < 2; ++l) {
    GemmTab gt; gt.nseg = 10;
    int gb = 0;
    for (int t = 0; t < 5; ++t) {
      size_t off = (size_t)(l * 5 + t);
      gt.s[2 * t + 0] = {xcb[STy[t]], Wlt + off * 16384, xlT[t], NN[STy[t]], gb};
      gb += (NN[STy[t]] + 63) / 64;
      gt.s[2 * t + 1] = {xcb[DTy[t]], Wrt + off * 16384, xrT[t], NN[DTy[t]], gb};
      gb += (NN[DTy[t]] + 63) / 64;
    }
    int fb = (l == 0) ? eb : 0;                 // layer 0: fill runs alongside gemm
    gemm_kernel<<<fb + gb, 256, 0, stream>>>(gt, etab, fb);

    // gat: longest segments first (station rel1 deg~30, worker rel4 deg~8, then task rels)
    GatTab at; at.nseg = 5;
    const int order[5] = {1, 4, 0, 2, 3};
    int wv = 0;
    for (int oi = 0; oi < 5; ++oi) {
      int t = order[oi];
      size_t off = (size_t)(l * 5 + t);
      at.s[oi] = {rowp[t], col[t], xlT[t], xrT[t], gatt + off * 256, gbias + off * 64,
                  aggOf[t], NN[DTy[t]], wv};
      wv += NN[DTy[t]];
    }
    gat_kernel<<<(wv * 64) / 256, 256, 0, stream>>>(at);

    if (l == 0) {
      combine_kernel<0><<<CB_ALL, 256, 0, stream>>>(
          (const float4*)aggT0, (const float4*)aggT2, (const float4*)aggT3,
          (const float4*)aggW, (const float4*)aggS,
          (const uint2*)xcb[0], (const uint2*)xcb[1], (const uint2*)xcb[2],
          nullptr, nullptr, nullptr,
          (uint2*)xcb[0], (uint2*)xcb[1], (uint2*)xcb[2],
          nullptr, nullptr);
    } else {
      combine_kernel<1><<<CB_ALL, 256, 0, stream>>>(
          (const float4*)aggT0, (const float4*)aggT2, (const float4*)aggT3,
          (const float4*)aggW, (const float4*)aggS,
          (const uint2*)xcb[0], (const uint2*)xcb[1], (const uint2*)xcb[2],
          (float4*)outT, (float4*)outW, (float4*)outS,
          nullptr, nullptr, nullptr,
          (float4*)psum, (float4*)pmax);
    }
  }

  // 3) final pool reduce
  pool2_kernel<<<3, 1024, 0, stream>>>(psum, pmax, gc);
}